// Round 12
// baseline (782.451 us; speedup 1.0000x reference)
//
#include <hip/hip_runtime.h>

#define NGRAPH  1024
#define E_EDGES 2097152
#define ECAP    2944
#define NB      64
#define CAPB    72
#define MAXZ    1000

__device__ __forceinline__ float bfu_lo(unsigned u) { return __uint_as_float(u << 16); }
__device__ __forceinline__ float bfu_hi(unsigned u) { return __uint_as_float(u & 0xFFFF0000u); }
__device__ __forceinline__ unsigned packlo(float f0, float f1) {
    return (__float_as_uint(f0) >> 16) | (__float_as_uint(f1) & 0xFFFF0000u);
}
// XOR-swizzled X indices (conflict-free vector access)
__device__ __forceinline__ int xh_idx(int r, int k)  { return (r << 6) | (k  ^ ((r & 7) << 3)); }
__device__ __forceinline__ int xl_idx(int r, int k2) { return (r << 5) | (k2 ^ ((r & 7) << 2)); }

// branchless double tanh via e^{2p}; abs error ~2e-13
__device__ __forceinline__ double tanh_fast(double p) {
    double q = 2.0 * p;
    q = fmin(40.0, fmax(-40.0, q));
    double nf = rint(q * 1.4426950408889634074);
    double r  = fma(nf, -6.93147180369123816490e-01, q);
    r = fma(nf, -1.90821492927058770002e-10, r);
    double er =     2.755731922398589e-07;
    er = fma(er, r, 2.755731922398589e-06);
    er = fma(er, r, 2.4801587301587302e-05);
    er = fma(er, r, 1.984126984126984e-04);
    er = fma(er, r, 1.3888888888888889e-03);
    er = fma(er, r, 8.333333333333333e-03);
    er = fma(er, r, 4.1666666666666664e-02);
    er = fma(er, r, 1.6666666666666666e-01);
    er = fma(er, r, 0.5);
    er = fma(er, r, 1.0);
    er = fma(er, r, 1.0);                        // e^r
    double E = er * __longlong_as_double((long long)(1023 + (int)nf) << 52);
    return 1.0 - 2.0 / (E + 1.0);
}

__global__ void markWS_kernel(float* out) {
    int i = blockIdx.x * 256 + threadIdx.x;
    if (i < NGRAPH) out[i] = 2.0f;
}

__global__ void bscatter_kernel(const int* __restrict__ ei,
                                unsigned* __restrict__ ecnt,
                                unsigned short* __restrict__ edges) {
    int e = blockIdx.x * 256 + threadIdx.x;
    if (e >= E_EDGES) return;
    int s = ei[e];
    int d = ei[E_EDGES + e];
    unsigned idx = (unsigned)((s >> 7) * NB + (e & (NB - 1)));
    unsigned pos = atomicAdd(&ecnt[idx], 1u);
    if (pos < CAPB) edges[(size_t)idx * CAPB + pos] = (unsigned short)((s & 127) | ((d & 127) << 8));
}

// 512 threads: rows {r0, r0+64} (r0 = t>>3), channels c0..c0+7 (c0 = (t&7)*8)
// Determinism: edge multiset -> packed adjacency COUNTS (commutative atomics) ->
// CSR emitted in ascending-s order => bitwise-reproducible output every launch.
__global__ __launch_bounds__(512, 2) void gnn_kernel(
    const int* __restrict__ z,
    const unsigned* __restrict__ ecnt, const unsigned short* __restrict__ edges,
    const float* __restrict__ zt,
    const float* __restrict__ W0, const float* __restrict__ b0,
    const float* __restrict__ W1, const float* __restrict__ b1,
    const float* __restrict__ W2, const float* __restrict__ b2,
    const float* __restrict__ W3, const float* __restrict__ b3,
    const float* __restrict__ c1w, const float* __restrict__ c1b,
    const float* __restrict__ c2w, const float* __restrict__ c2b,
    const float* __restrict__ l1w, const float* __restrict__ l1b,
    const float* __restrict__ l2w, const float* __restrict__ l2b,
    float* __restrict__ out)
{
    __shared__ __align__(16) float    Xhi[8192];   // 32768 B (adjM overlay during setup)
    __shared__ __align__(16) unsigned Xlo[4096];   // 16384 B (h4s/key/G1/head overlays)
    __shared__ __align__(16) float    Wf[2048];    //  8192 B
    __shared__ unsigned char  csr[ECAP];           //  2944 B
    __shared__ unsigned short rp16[132];
    __shared__ int            aux[128];            // degree
    __shared__ int            bc[NB];
    __shared__ int            inv[30];
    __shared__ float          kd30f[30];
    __shared__ int            w0tot;
    // ~61.5 KB -> 2 blocks/CU

    const int g  = blockIdx.x;
    const int t  = threadIdx.x;
    const int r0 = t >> 3;
    const int r1 = r0 + 64;
    const int c0 = (t & 7) << 3;
    const unsigned gb = (unsigned)g * NB;

    unsigned* adjM = (unsigned*)Xhi;   // [128][32] packed byte counts (16 KB)

    for (int i = t; i < 4096; i += 512) adjM[i] = 0u;
    if (t < NB) { unsigned n = ecnt[gb + t]; bc[t] = (n > CAPB) ? CAPB : (int)n; }
    if (t < 30) { inv[t] = t; kd30f[t] = 0.f; }
    __syncthreads();

    // order-independent edge counting
    for (int slot = t; slot < NB * CAPB; slot += 512) {
        int b = slot / CAPB, i = slot - b * CAPB;
        if (i < bc[b]) {
            unsigned short ev = edges[(size_t)(gb + b) * CAPB + i];
            int s = ev & 127, d = (ev >> 8) & 127;
            atomicAdd(&adjM[(d << 5) + (s >> 2)], 1u << ((s & 3) << 3));
        }
    }
    __syncthreads();

    // per-node in-degree from adjM
    int degv = 0;
    if (t < 128) {
        for (int w = 0; w < 32; ++w) {
            unsigned u = adjM[(t << 5) + w];
            degv += (int)((u & 255u) + ((u >> 8) & 255u) + ((u >> 16) & 255u) + (u >> 24));
        }
        aux[t] = degv;
    }
    // exclusive scan of degrees (two waves, shfl)
    if (t < 128) {
        int v = degv;
        for (int o = 1; o < 64; o <<= 1) {
            int u = __shfl_up(v, o, 64);
            if ((t & 63) >= o) v += u;
        }
        if (t == 63) w0tot = v;
        rp16[t + 1] = (unsigned short)v;
    }
    __syncthreads();
    if (t >= 64 && t < 128) rp16[t + 1] = (unsigned short)(rp16[t + 1] + w0tot);
    if (t == 0) rp16[0] = 0;
    __syncthreads();

    const int mydeg = (t < 128) ? aux[t] : 0;
    const double dv0 = 1.0 / sqrt((double)(aux[r0] + 1));
    const double dv1 = 1.0 / sqrt((double)(aux[r1] + 1));
    const double dvm = 1.0 / sqrt((double)(mydeg + 1));

    // deterministic CSR emit (s ascending, multiplicity preserved)
    if (t < 128) {
        unsigned pos = rp16[t];
        for (int w = 0; w < 32; ++w) {
            unsigned u = adjM[(t << 5) + w];
            while (u) {
                // lowest nonzero byte lane
                int b2 = (u & 0xFFu) ? 0 : (u & 0xFF00u) ? 1 : (u & 0xFF0000u) ? 2 : 3;
                int m = (int)((u >> (b2 << 3)) & 255u);
                unsigned char sv = (unsigned char)((w << 2) + b2);
                for (int q = 0; q < m; ++q) { if (pos < ECAP) csr[pos] = sv; ++pos; }
                u &= ~(0xFFu << (b2 << 3));
            }
        }
    }
    __syncthreads();                 // adjM reads done; Xhi free

    // X0 = z_table[z] (bf16-exact f32; lo path skipped in layer 0)
    for (int idx = t; idx < 8192; idx += 512) {
        int n = idx >> 6, c = idx & 63;
        int zv = z[(g << 7) + n];
        zv = (zv < 0) ? 0 : ((zv >= MAXZ) ? MAXZ - 1 : zv);
        Xhi[xh_idx(n, c)] = zt[zv * 64 + c];
    }
    __syncthreads();

    float g1p[2][16];
#pragma unroll
    for (int rw = 0; rw < 2; ++rw)
#pragma unroll
        for (int c = 0; c < 16; ++c) g1p[rw][c] = 0.f;

    // ---- three GCN layers ----
    for (int layer = 0; layer < 3; ++layer) {
        const float* Wg = (layer == 0) ? W0 : (layer == 1) ? W1 : W2;
        const float* bg = (layer == 0) ? b0 : (layer == 1) ? b1 : b2;
        const bool haslo = (layer != 0);

        // phase 1: acc = (X @ W)[r0,r1][c0..c0+7]; weights staged per half in LDS
        double accd0[8], accd1[8]; float accf0[8], accf1[8];
#pragma unroll
        for (int j = 0; j < 8; ++j) { accd0[j] = 0.0; accd1[j] = 0.0; accf0[j] = 0.f; accf1[j] = 0.f; }

        for (int half = 0; half < 2; ++half) {
            __syncthreads();
            ((float4*)Wf)[t] = ((const float4*)(Wg + (half << 11)))[t];
            __syncthreads();
            for (int k4 = 0; k4 < 32; k4 += 4) {
                int k = (half << 5) + k4;
                float4 a0 = *(const float4*)&Xhi[xh_idx(r0, k)];
                float4 a1 = *(const float4*)&Xhi[xh_idx(r1, k)];
                float x0[4] = {a0.x, a0.y, a0.z, a0.w};
                float x1[4] = {a1.x, a1.y, a1.z, a1.w};
                float l0[4], l1[4];
                if (haslo) {
                    uint2 u0 = *(const uint2*)&Xlo[xl_idx(r0, k >> 1)];
                    uint2 u1 = *(const uint2*)&Xlo[xl_idx(r1, k >> 1)];
                    l0[0] = bfu_lo(u0.x); l0[1] = bfu_hi(u0.x); l0[2] = bfu_lo(u0.y); l0[3] = bfu_hi(u0.y);
                    l1[0] = bfu_lo(u1.x); l1[1] = bfu_hi(u1.x); l1[2] = bfu_lo(u1.y); l1[3] = bfu_hi(u1.y);
                }
#pragma unroll
                for (int kk = 0; kk < 4; ++kk) {
                    const float* wr = &Wf[((k4 + kk) << 6) + c0];
                    float4 wa = *(const float4*)wr;
                    float4 wb = *(const float4*)(wr + 4);
                    float wf[8] = {wa.x, wa.y, wa.z, wa.w, wb.x, wb.y, wb.z, wb.w};
                    double xd0 = (double)x0[kk], xd1 = (double)x1[kk];
#pragma unroll
                    for (int j = 0; j < 8; ++j) {
                        double wd = (double)wf[j];
                        accd0[j] = fma(xd0, wd, accd0[j]);
                        accd1[j] = fma(xd1, wd, accd1[j]);
                    }
                    if (haslo) {
#pragma unroll
                        for (int j = 0; j < 8; ++j) {
                            accf0[j] = fmaf(l0[kk], wf[j], accf0[j]);
                            accf1[j] = fmaf(l1[kk], wf[j], accf1[j]);
                        }
                    }
                }
            }
        }
        __syncthreads();                                   // all X reads complete

        // H = dinv * acc; store hi/lo
        float hfv[2][8], rsv[2][8];
#pragma unroll
        for (int rw = 0; rw < 2; ++rw) {
            int rr = rw ? r1 : r0;
            double dv = rw ? dv1 : dv0;
#pragma unroll
            for (int j = 0; j < 8; ++j) {
                double acc = rw ? (accd1[j] + (double)accf1[j]) : (accd0[j] + (double)accf0[j]);
                double h = dv * acc;
                float hf = (float)h;
                hfv[rw][j] = hf;
                rsv[rw][j] = (float)(h - (double)hf);
            }
            int bi = xh_idx(rr, c0);
            *(float4*)&Xhi[bi]     = make_float4(hfv[rw][0], hfv[rw][1], hfv[rw][2], hfv[rw][3]);
            *(float4*)&Xhi[bi + 4] = make_float4(hfv[rw][4], hfv[rw][5], hfv[rw][6], hfv[rw][7]);
            uint4 lv;
            lv.x = packlo(rsv[rw][0], rsv[rw][1]);
            lv.y = packlo(rsv[rw][2], rsv[rw][3]);
            lv.z = packlo(rsv[rw][4], rsv[rw][5]);
            lv.w = packlo(rsv[rw][6], rsv[rw][7]);
            *(uint4*)&Xlo[xl_idx(rr, c0 >> 1)] = lv;
        }
        __syncthreads();                                   // H fully written

        // phase 2: agg = H[own] + sum_neighbors H[s] (deterministic order)
        double ad[2][8]; float af[2][8];
#pragma unroll
        for (int rw = 0; rw < 2; ++rw)
#pragma unroll
            for (int j = 0; j < 8; ++j) { ad[rw][j] = (double)hfv[rw][j]; af[rw][j] = rsv[rw][j]; }

#pragma unroll
        for (int rw = 0; rw < 2; ++rw) {
            int rr = rw ? r1 : r0;
            for (unsigned e = rp16[rr]; e < rp16[rr + 1]; ++e) {
                int s = csr[e];
                int bi = (s << 6) | (c0 ^ ((s & 7) << 3));
                float4 a = *(const float4*)&Xhi[bi];
                float4 b = *(const float4*)&Xhi[bi + 4];
                uint4 lu = *(const uint4*)&Xlo[(s << 5) | ((c0 >> 1) ^ ((s & 7) << 2))];
                ad[rw][0] += (double)a.x; ad[rw][1] += (double)a.y;
                ad[rw][2] += (double)a.z; ad[rw][3] += (double)a.w;
                ad[rw][4] += (double)b.x; ad[rw][5] += (double)b.y;
                ad[rw][6] += (double)b.z; ad[rw][7] += (double)b.w;
                af[rw][0] += bfu_lo(lu.x); af[rw][1] += bfu_hi(lu.x);
                af[rw][2] += bfu_lo(lu.y); af[rw][3] += bfu_hi(lu.y);
                af[rw][4] += bfu_lo(lu.z); af[rw][5] += bfu_hi(lu.z);
                af[rw][6] += bfu_lo(lu.w); af[rw][7] += bfu_hi(lu.w);
            }
        }
        __syncthreads();                                   // all H reads complete

        // X = tanh(dinv*agg + b); fused conv1 partial accumulate
#pragma unroll
        for (int rw = 0; rw < 2; ++rw) {
            int rr = rw ? r1 : r0;
            double dv = rw ? dv1 : dv0;
            float vf[8], rs[8];
#pragma unroll
            for (int j = 0; j < 8; ++j) {
                double v = tanh_fast(dv * (ad[rw][j] + (double)af[rw][j]) + (double)bg[c0 + j]);
                float vfl = (float)v;
                vf[j] = vfl;
                rs[j] = (float)(v - (double)vfl);
            }
            int bi = xh_idx(rr, c0);
            *(float4*)&Xhi[bi]     = make_float4(vf[0], vf[1], vf[2], vf[3]);
            *(float4*)&Xhi[bi + 4] = make_float4(vf[4], vf[5], vf[6], vf[7]);
            uint4 lv;
            lv.x = packlo(rs[0], rs[1]);
            lv.y = packlo(rs[2], rs[3]);
            lv.z = packlo(rs[4], rs[5]);
            lv.w = packlo(rs[6], rs[7]);
            *(uint4*)&Xlo[xl_idx(rr, c0 >> 1)] = lv;

            const float* w1base = c1w + layer * 64 + c0;
            for (int c = 0; c < 16; ++c) {
                const float* wr = w1base + c * 193;
#pragma unroll
                for (int j = 0; j < 8; ++j)
                    g1p[rw][c] = fmaf(vf[j], wr[j], g1p[rw][c]);
            }
        }
        __syncthreads();
    }

    // ---- layer 4 (64->1): key path; overlays on dead Xlo ----
    double* h4sD  = (double*)Xlo;
    double* keydD = ((double*)Xlo) + 128;

    double sdreg = 0.0;
    if (t < 128) {
        double sd = 0.0; float sf = 0.f;
        for (int k = 0; k < 64; k += 4) {
            float4 a = *(const float4*)&Xhi[xh_idx(t, k)];
            uint2  u = *(const uint2*)&Xlo[xl_idx(t, k >> 1)];
            float4 w = *(const float4*)&W3[k];
            sd = fma((double)a.x, (double)w.x, sd);
            sd = fma((double)a.y, (double)w.y, sd);
            sd = fma((double)a.z, (double)w.z, sd);
            sd = fma((double)a.w, (double)w.w, sd);
            sf = fmaf(bfu_lo(u.x), w.x, sf);
            sf = fmaf(bfu_hi(u.x), w.y, sf);
            sf = fmaf(bfu_lo(u.y), w.z, sf);
            sf = fmaf(bfu_hi(u.y), w.w, sf);
        }
        sdreg = sd + (double)sf;
    }
    __syncthreads();                          // Xlo reads done before overlay write
    if (t < 128) h4sD[t] = dvm * sdreg;
    __syncthreads();
    double keyreg = 0.0;
    if (t < 128) {
        double a = h4sD[t];
        for (unsigned e = rp16[t]; e < rp16[t + 1]; ++e) a += h4sD[csr[e]];
        keyreg = tanh_fast(dvm * a + (double)b3[0]);
        keydD[t] = keyreg;
    }
    __syncthreads();

    // stable descending rank == stable argsort(-key)
    if (t < 128) {
        int rk = 0;
        for (int j = 0; j < 128; ++j) {
            double kj = keydD[j];
            if (kj > keyreg || (kj == keyreg && j < t)) ++rk;
        }
        if (rk < 30) { inv[rk] = t; kd30f[rk] = (float)keyreg; }
    }

    // reduce conv1 partials across 8 channel-lanes
#pragma unroll
    for (int m = 1; m <= 4; m <<= 1) {
#pragma unroll
        for (int rw = 0; rw < 2; ++rw)
#pragma unroll
            for (int c = 0; c < 16; ++c)
                g1p[rw][c] += __shfl_xor(g1p[rw][c], m, 64);
    }
    __syncthreads();
    float* XloF = (float*)Xlo;
    float* G1   = XloF + 512;                // 2048 floats
    if ((t & 7) == 0) {
#pragma unroll
        for (int c = 0; c < 16; c += 4) {
            *(float4*)&G1[r0 * 16 + c] = make_float4(g1p[0][c], g1p[0][c + 1], g1p[0][c + 2], g1p[0][c + 3]);
            *(float4*)&G1[r1 * 16 + c] = make_float4(g1p[1][c], g1p[1][c + 1], g1p[1][c + 2], g1p[1][c + 3]);
        }
    }
    __syncthreads();

    // ---- head ----
    float* h1v = XloF + 2560;   // 480
    float* ppv = XloF + 3040;   // 240
    float* flv = XloF + 3280;   // 352
    float* hmv = XloF + 3632;   // 128

    if (t < 480) {
        int c = t & 15, k = t >> 4;
        int node = inv[k];
        float s = G1[node * 16 + c] + c1w[c * 193 + 192] * kd30f[k] + c1b[c];
        h1v[c * 30 + k] = s > 0.f ? s : 0.f;
    }
    __syncthreads();
    if (t < 240) {
        int c = t & 15, i = t >> 4;
        float a = h1v[c * 30 + 2 * i], b = h1v[c * 30 + 2 * i + 1];
        ppv[c * 15 + i] = a > b ? a : b;
    }
    __syncthreads();
    if (t < 352) {
        int o = t / 11, j = t % 11;
        float s = c2b[o];
        for (int i = 0; i < 16; ++i)
#pragma unroll
            for (int u = 0; u < 5; ++u)
                s = fmaf(ppv[i * 15 + j + u], c2w[o * 80 + i * 5 + u], s);
        flv[t] = s > 0.f ? s : 0.f;
    }
    __syncthreads();
    if (t < 128) {
        float s = l1b[t];
        for (int i = 0; i < 352; ++i) s = fmaf(flv[i], l1w[i * 128 + t], s);
        hmv[t] = s > 0.f ? s : 0.f;
    }
    __syncthreads();
    if (t < 64) {
        float v = fmaf(hmv[t], l2w[t], hmv[t + 64] * l2w[t + 64]);
#pragma unroll
        for (int o = 32; o > 0; o >>= 1) v += __shfl_down(v, o, 64);
        if (t == 0) out[g] = v + l2b[0];
    }
}

// ---------------- launch ----------------

extern "C" void kernel_launch(void* const* d_in, const int* in_sizes, int n_in,
                              void* d_out, int out_size, void* d_ws, size_t ws_size,
                              hipStream_t stream) {
    const int*   z   = (const int*)d_in[0];
    const int*   ei  = (const int*)d_in[1];
    const float* zt  = (const float*)d_in[3];
    const float* W0  = (const float*)d_in[4];
    const float* b0  = (const float*)d_in[5];
    const float* W1  = (const float*)d_in[6];
    const float* b1  = (const float*)d_in[7];
    const float* W2  = (const float*)d_in[8];
    const float* b2  = (const float*)d_in[9];
    const float* W3  = (const float*)d_in[10];
    const float* b3  = (const float*)d_in[11];
    const float* c1w = (const float*)d_in[12];
    const float* c1b = (const float*)d_in[13];
    const float* c2w = (const float*)d_in[14];
    const float* c2b = (const float*)d_in[15];
    const float* l1w = (const float*)d_in[16];
    const float* l1b = (const float*)d_in[17];
    const float* l2w = (const float*)d_in[18];
    const float* l2b = (const float*)d_in[19];
    float* out = (float*)d_out;

    const size_t ECNT_B = (size_t)NGRAPH * NB * 4;                   // 256 KB
    const size_t NEEDED = ECNT_B + (size_t)NGRAPH * NB * CAPB * 2;   // ~9.7 MB
    if (ws_size < NEEDED) {
        markWS_kernel<<<4, 256, 0, stream>>>(out);
        return;
    }

    unsigned*       ecnt  = (unsigned*)d_ws;
    unsigned short* edges = (unsigned short*)((char*)d_ws + ECNT_B);

    hipMemsetAsync(ecnt, 0, ECNT_B, stream);
    bscatter_kernel<<<(E_EDGES + 255) / 256, 256, 0, stream>>>(ei, ecnt, edges);

    gnn_kernel<<<NGRAPH, 512, 0, stream>>>(z, ecnt, edges, zt,
                                           W0, b0, W1, b1, W2, b2, W3, b3,
                                           c1w, c1b, c2w, c2b, l1w, l1b, l2w, l2b,
                                           out);
}

// Round 13
// 695.265 us; speedup vs baseline: 1.1254x; 1.1254x over previous
//
#include <hip/hip_runtime.h>

#define NGRAPH  1024
#define E_EDGES 2097152
#define ECAP    2944
#define MAXZ    1000

__device__ __forceinline__ float bfu_lo(unsigned u) { return __uint_as_float(u << 16); }
__device__ __forceinline__ float bfu_hi(unsigned u) { return __uint_as_float(u & 0xFFFF0000u); }
__device__ __forceinline__ unsigned packlo(float f0, float f1) {
    return (__float_as_uint(f0) >> 16) | (__float_as_uint(f1) & 0xFFFF0000u);
}
// XOR-swizzled X indices (conflict-free vector access)
__device__ __forceinline__ int xh_idx(int r, int k)  { return (r << 6) | (k  ^ ((r & 7) << 3)); }
__device__ __forceinline__ int xl_idx(int r, int k2) { return (r << 5) | (k2 ^ ((r & 7) << 2)); }

// branchless double tanh via e^{2p}; abs error ~2e-13
__device__ __forceinline__ double tanh_fast(double p) {
    double q = 2.0 * p;
    q = fmin(40.0, fmax(-40.0, q));
    double nf = rint(q * 1.4426950408889634074);
    double r  = fma(nf, -6.93147180369123816490e-01, q);
    r = fma(nf, -1.90821492927058770002e-10, r);
    double er =     2.755731922398589e-07;
    er = fma(er, r, 2.755731922398589e-06);
    er = fma(er, r, 2.4801587301587302e-05);
    er = fma(er, r, 1.984126984126984e-04);
    er = fma(er, r, 1.3888888888888889e-03);
    er = fma(er, r, 8.333333333333333e-03);
    er = fma(er, r, 4.1666666666666664e-02);
    er = fma(er, r, 1.6666666666666666e-01);
    er = fma(er, r, 0.5);
    er = fma(er, r, 1.0);
    er = fma(er, r, 1.0);                        // e^r
    double E = er * __longlong_as_double((long long)(1023 + (int)nf) << 52);
    return 1.0 - 2.0 / (E + 1.0);
}

__global__ void markWS_kernel(float* out) {
    int i = blockIdx.x * 256 + threadIdx.x;
    if (i < NGRAPH) out[i] = 2.0f;
}

// packed adjacency counts, directly in global: adjG[g][d][s/4] byte-lane (s&3)
// commutative integer atomics -> bitwise-deterministic adjacency
__global__ void adjscatter_kernel(const int* __restrict__ ei,
                                  unsigned* __restrict__ adjG) {
    int e = blockIdx.x * 256 + threadIdx.x;
    if (e >= E_EDGES) return;
    int s = ei[e];
    int d = ei[E_EDGES + e];
    int g = s >> 7;
    int sl = s & 127, dl = d & 127;
    atomicAdd(&adjG[((size_t)g << 12) + (dl << 5) + (sl >> 2)], 1u << ((sl & 3) << 3));
}

// 512 threads: rows {r0, r0+64} (r0 = t>>3), channels c0..c0+7 (c0 = (t&7)*8)
__global__ __launch_bounds__(512, 2) void gnn_kernel(
    const int* __restrict__ z,
    const unsigned* __restrict__ adjG,
    const float* __restrict__ zt,
    const float* __restrict__ W0, const float* __restrict__ b0,
    const float* __restrict__ W1, const float* __restrict__ b1,
    const float* __restrict__ W2, const float* __restrict__ b2,
    const float* __restrict__ W3, const float* __restrict__ b3,
    const float* __restrict__ c1w, const float* __restrict__ c1b,
    const float* __restrict__ c2w, const float* __restrict__ c2b,
    const float* __restrict__ l1w, const float* __restrict__ l1b,
    const float* __restrict__ l2w, const float* __restrict__ l2b,
    float* __restrict__ out)
{
    __shared__ __align__(16) float    Xhi[8192];   // 32768 B (adjM overlay during setup)
    __shared__ __align__(16) unsigned Xlo[4096];   // 16384 B (h4s/key/G1/head overlays)
    __shared__ __align__(16) float    Wf[2048];    //  8192 B
    __shared__ unsigned char  csr[ECAP];           //  2944 B
    __shared__ unsigned short rp16[132];
    __shared__ int            aux[128];            // degree
    __shared__ int            inv[30];
    __shared__ float          kd30f[30];
    __shared__ int            w0tot;
    // ~61.2 KB -> 2 blocks/CU

    const int g  = blockIdx.x;
    const int t  = threadIdx.x;
    const int r0 = t >> 3;
    const int r1 = r0 + 64;
    const int c0 = (t & 7) << 3;

    unsigned* adjM = (unsigned*)Xhi;   // [128][32] packed byte counts (16 KB)

    // load this graph's adjacency-count slab (coalesced)
    {
        const uint4* src = (const uint4*)(adjG + ((size_t)g << 12));
        uint4* dst = (uint4*)adjM;
        for (int i = t; i < 1024; i += 512) dst[i] = src[i];
    }
    if (t < 30) { inv[t] = t; kd30f[t] = 0.f; }
    __syncthreads();

    // per-node in-degree from adjM
    int degv = 0;
    if (t < 128) {
        for (int w = 0; w < 32; ++w) {
            unsigned u = adjM[(t << 5) + w];
            degv += (int)((u & 255u) + ((u >> 8) & 255u) + ((u >> 16) & 255u) + (u >> 24));
        }
        aux[t] = degv;
    }
    // exclusive scan of degrees (two waves, shfl)
    if (t < 128) {
        int v = degv;
        for (int o = 1; o < 64; o <<= 1) {
            int u = __shfl_up(v, o, 64);
            if ((t & 63) >= o) v += u;
        }
        if (t == 63) w0tot = v;
        rp16[t + 1] = (unsigned short)v;
    }
    __syncthreads();
    if (t >= 64 && t < 128) rp16[t + 1] = (unsigned short)(rp16[t + 1] + w0tot);
    if (t == 0) rp16[0] = 0;
    __syncthreads();

    const int mydeg = (t < 128) ? aux[t] : 0;
    const double dv0 = 1.0 / sqrt((double)(aux[r0] + 1));
    const double dv1 = 1.0 / sqrt((double)(aux[r1] + 1));
    const double dvm = 1.0 / sqrt((double)(mydeg + 1));

    // deterministic CSR emit (s ascending, multiplicity preserved)
    if (t < 128) {
        unsigned pos = rp16[t];
        for (int w = 0; w < 32; ++w) {
            unsigned u = adjM[(t << 5) + w];
            while (u) {
                int b2 = (u & 0xFFu) ? 0 : (u & 0xFF00u) ? 1 : (u & 0xFF0000u) ? 2 : 3;
                int m = (int)((u >> (b2 << 3)) & 255u);
                unsigned char sv = (unsigned char)((w << 2) + b2);
                for (int q = 0; q < m; ++q) { if (pos < ECAP) csr[pos] = sv; ++pos; }
                u &= ~(0xFFu << (b2 << 3));
            }
        }
    }
    __syncthreads();                 // adjM reads done; Xhi free

    // X0 = z_table[z] (bf16-exact f32; lo path skipped in layer 0)
    for (int idx = t; idx < 8192; idx += 512) {
        int n = idx >> 6, c = idx & 63;
        int zv = z[(g << 7) + n];
        zv = (zv < 0) ? 0 : ((zv >= MAXZ) ? MAXZ - 1 : zv);
        Xhi[xh_idx(n, c)] = zt[zv * 64 + c];
    }
    __syncthreads();

    float g1p[2][16];
#pragma unroll
    for (int rw = 0; rw < 2; ++rw)
#pragma unroll
        for (int c = 0; c < 16; ++c) g1p[rw][c] = 0.f;

    // ---- three GCN layers ----
    for (int layer = 0; layer < 3; ++layer) {
        const float* Wg = (layer == 0) ? W0 : (layer == 1) ? W1 : W2;
        const float* bg = (layer == 0) ? b0 : (layer == 1) ? b1 : b2;
        const bool haslo = (layer != 0);

        // phase 1: acc = (X @ W)[r0,r1][c0..c0+7]; weights staged per half in LDS
        double accd0[8], accd1[8]; float accf0[8], accf1[8];
#pragma unroll
        for (int j = 0; j < 8; ++j) { accd0[j] = 0.0; accd1[j] = 0.0; accf0[j] = 0.f; accf1[j] = 0.f; }

        for (int half = 0; half < 2; ++half) {
            __syncthreads();
            ((float4*)Wf)[t] = ((const float4*)(Wg + (half << 11)))[t];
            __syncthreads();
            for (int k4 = 0; k4 < 32; k4 += 4) {
                int k = (half << 5) + k4;
                float4 a0 = *(const float4*)&Xhi[xh_idx(r0, k)];
                float4 a1 = *(const float4*)&Xhi[xh_idx(r1, k)];
                float x0[4] = {a0.x, a0.y, a0.z, a0.w};
                float x1[4] = {a1.x, a1.y, a1.z, a1.w};
                float l0[4], l1[4];
                if (haslo) {
                    uint2 u0 = *(const uint2*)&Xlo[xl_idx(r0, k >> 1)];
                    uint2 u1 = *(const uint2*)&Xlo[xl_idx(r1, k >> 1)];
                    l0[0] = bfu_lo(u0.x); l0[1] = bfu_hi(u0.x); l0[2] = bfu_lo(u0.y); l0[3] = bfu_hi(u0.y);
                    l1[0] = bfu_lo(u1.x); l1[1] = bfu_hi(u1.x); l1[2] = bfu_lo(u1.y); l1[3] = bfu_hi(u1.y);
                }
#pragma unroll
                for (int kk = 0; kk < 4; ++kk) {
                    const float* wr = &Wf[((k4 + kk) << 6) + c0];
                    float4 wa = *(const float4*)wr;
                    float4 wb = *(const float4*)(wr + 4);
                    float wf[8] = {wa.x, wa.y, wa.z, wa.w, wb.x, wb.y, wb.z, wb.w};
                    double xd0 = (double)x0[kk], xd1 = (double)x1[kk];
#pragma unroll
                    for (int j = 0; j < 8; ++j) {
                        double wd = (double)wf[j];
                        accd0[j] = fma(xd0, wd, accd0[j]);
                        accd1[j] = fma(xd1, wd, accd1[j]);
                    }
                    if (haslo) {
#pragma unroll
                        for (int j = 0; j < 8; ++j) {
                            accf0[j] = fmaf(l0[kk], wf[j], accf0[j]);
                            accf1[j] = fmaf(l1[kk], wf[j], accf1[j]);
                        }
                    }
                }
            }
        }
        __syncthreads();                                   // all X reads complete

        // H = dinv * acc; store hi/lo
        float hfv[2][8], rsv[2][8];
#pragma unroll
        for (int rw = 0; rw < 2; ++rw) {
            int rr = rw ? r1 : r0;
            double dv = rw ? dv1 : dv0;
#pragma unroll
            for (int j = 0; j < 8; ++j) {
                double acc = rw ? (accd1[j] + (double)accf1[j]) : (accd0[j] + (double)accf0[j]);
                double h = dv * acc;
                float hf = (float)h;
                hfv[rw][j] = hf;
                rsv[rw][j] = (float)(h - (double)hf);
            }
            int bi = xh_idx(rr, c0);
            *(float4*)&Xhi[bi]     = make_float4(hfv[rw][0], hfv[rw][1], hfv[rw][2], hfv[rw][3]);
            *(float4*)&Xhi[bi + 4] = make_float4(hfv[rw][4], hfv[rw][5], hfv[rw][6], hfv[rw][7]);
            uint4 lv;
            lv.x = packlo(rsv[rw][0], rsv[rw][1]);
            lv.y = packlo(rsv[rw][2], rsv[rw][3]);
            lv.z = packlo(rsv[rw][4], rsv[rw][5]);
            lv.w = packlo(rsv[rw][6], rsv[rw][7]);
            *(uint4*)&Xlo[xl_idx(rr, c0 >> 1)] = lv;
        }
        __syncthreads();                                   // H fully written

        // phase 2: agg = H[own] + sum_neighbors H[s] (deterministic order)
        double ad[2][8]; float af[2][8];
#pragma unroll
        for (int rw = 0; rw < 2; ++rw)
#pragma unroll
            for (int j = 0; j < 8; ++j) { ad[rw][j] = (double)hfv[rw][j]; af[rw][j] = rsv[rw][j]; }

#pragma unroll
        for (int rw = 0; rw < 2; ++rw) {
            int rr = rw ? r1 : r0;
            for (unsigned e = rp16[rr]; e < rp16[rr + 1]; ++e) {
                int s = csr[e];
                int bi = (s << 6) | (c0 ^ ((s & 7) << 3));
                float4 a = *(const float4*)&Xhi[bi];
                float4 b = *(const float4*)&Xhi[bi + 4];
                uint4 lu = *(const uint4*)&Xlo[(s << 5) | ((c0 >> 1) ^ ((s & 7) << 2))];
                ad[rw][0] += (double)a.x; ad[rw][1] += (double)a.y;
                ad[rw][2] += (double)a.z; ad[rw][3] += (double)a.w;
                ad[rw][4] += (double)b.x; ad[rw][5] += (double)b.y;
                ad[rw][6] += (double)b.z; ad[rw][7] += (double)b.w;
                af[rw][0] += bfu_lo(lu.x); af[rw][1] += bfu_hi(lu.x);
                af[rw][2] += bfu_lo(lu.y); af[rw][3] += bfu_hi(lu.y);
                af[rw][4] += bfu_lo(lu.z); af[rw][5] += bfu_hi(lu.z);
                af[rw][6] += bfu_lo(lu.w); af[rw][7] += bfu_hi(lu.w);
            }
        }
        __syncthreads();                                   // all H reads complete

        // X = tanh(dinv*agg + b); fused conv1 partial accumulate
#pragma unroll
        for (int rw = 0; rw < 2; ++rw) {
            int rr = rw ? r1 : r0;
            double dv = rw ? dv1 : dv0;
            float vf[8], rs[8];
#pragma unroll
            for (int j = 0; j < 8; ++j) {
                double v = tanh_fast(dv * (ad[rw][j] + (double)af[rw][j]) + (double)bg[c0 + j]);
                float vfl = (float)v;
                vf[j] = vfl;
                rs[j] = (float)(v - (double)vfl);
            }
            int bi = xh_idx(rr, c0);
            *(float4*)&Xhi[bi]     = make_float4(vf[0], vf[1], vf[2], vf[3]);
            *(float4*)&Xhi[bi + 4] = make_float4(vf[4], vf[5], vf[6], vf[7]);
            uint4 lv;
            lv.x = packlo(rs[0], rs[1]);
            lv.y = packlo(rs[2], rs[3]);
            lv.z = packlo(rs[4], rs[5]);
            lv.w = packlo(rs[6], rs[7]);
            *(uint4*)&Xlo[xl_idx(rr, c0 >> 1)] = lv;

            const float* w1base = c1w + layer * 64 + c0;
            for (int c = 0; c < 16; ++c) {
                const float* wr = w1base + c * 193;
#pragma unroll
                for (int j = 0; j < 8; ++j)
                    g1p[rw][c] = fmaf(vf[j], wr[j], g1p[rw][c]);
            }
        }
        __syncthreads();
    }

    // ---- layer 4 (64->1): key path; overlays on dead Xlo ----
    double* h4sD  = (double*)Xlo;
    double* keydD = ((double*)Xlo) + 128;

    double sdreg = 0.0;
    if (t < 128) {
        double sd = 0.0; float sf = 0.f;
        for (int k = 0; k < 64; k += 4) {
            float4 a = *(const float4*)&Xhi[xh_idx(t, k)];
            uint2  u = *(const uint2*)&Xlo[xl_idx(t, k >> 1)];
            float4 w = *(const float4*)&W3[k];
            sd = fma((double)a.x, (double)w.x, sd);
            sd = fma((double)a.y, (double)w.y, sd);
            sd = fma((double)a.z, (double)w.z, sd);
            sd = fma((double)a.w, (double)w.w, sd);
            sf = fmaf(bfu_lo(u.x), w.x, sf);
            sf = fmaf(bfu_hi(u.x), w.y, sf);
            sf = fmaf(bfu_lo(u.y), w.z, sf);
            sf = fmaf(bfu_hi(u.y), w.w, sf);
        }
        sdreg = sd + (double)sf;
    }
    __syncthreads();                          // Xlo reads done before overlay write
    if (t < 128) h4sD[t] = dvm * sdreg;
    __syncthreads();
    double keyreg = 0.0;
    if (t < 128) {
        double a = h4sD[t];
        for (unsigned e = rp16[t]; e < rp16[t + 1]; ++e) a += h4sD[csr[e]];
        keyreg = tanh_fast(dvm * a + (double)b3[0]);
        keydD[t] = keyreg;
    }
    __syncthreads();

    // stable descending rank == stable argsort(-key)
    if (t < 128) {
        int rk = 0;
        for (int j = 0; j < 128; ++j) {
            double kj = keydD[j];
            if (kj > keyreg || (kj == keyreg && j < t)) ++rk;
        }
        if (rk < 30) { inv[rk] = t; kd30f[rk] = (float)keyreg; }
    }

    // reduce conv1 partials across 8 channel-lanes
#pragma unroll
    for (int m = 1; m <= 4; m <<= 1) {
#pragma unroll
        for (int rw = 0; rw < 2; ++rw)
#pragma unroll
            for (int c = 0; c < 16; ++c)
                g1p[rw][c] += __shfl_xor(g1p[rw][c], m, 64);
    }
    __syncthreads();
    float* XloF = (float*)Xlo;
    float* G1   = XloF + 512;                // 2048 floats
    if ((t & 7) == 0) {
#pragma unroll
        for (int c = 0; c < 16; c += 4) {
            *(float4*)&G1[r0 * 16 + c] = make_float4(g1p[0][c], g1p[0][c + 1], g1p[0][c + 2], g1p[0][c + 3]);
            *(float4*)&G1[r1 * 16 + c] = make_float4(g1p[1][c], g1p[1][c + 1], g1p[1][c + 2], g1p[1][c + 3]);
        }
    }
    __syncthreads();

    // ---- head ----
    float* h1v = XloF + 2560;   // 480
    float* ppv = XloF + 3040;   // 240
    float* flv = XloF + 3280;   // 352
    float* hmv = XloF + 3632;   // 128

    if (t < 480) {
        int c = t & 15, k = t >> 4;
        int node = inv[k];
        float s = G1[node * 16 + c] + c1w[c * 193 + 192] * kd30f[k] + c1b[c];
        h1v[c * 30 + k] = s > 0.f ? s : 0.f;
    }
    __syncthreads();
    if (t < 240) {
        int c = t & 15, i = t >> 4;
        float a = h1v[c * 30 + 2 * i], b = h1v[c * 30 + 2 * i + 1];
        ppv[c * 15 + i] = a > b ? a : b;
    }
    __syncthreads();
    if (t < 352) {
        int o = t / 11, j = t % 11;
        float s = c2b[o];
        for (int i = 0; i < 16; ++i)
#pragma unroll
            for (int u = 0; u < 5; ++u)
                s = fmaf(ppv[i * 15 + j + u], c2w[o * 80 + i * 5 + u], s);
        flv[t] = s > 0.f ? s : 0.f;
    }
    __syncthreads();
    if (t < 128) {
        float s = l1b[t];
        for (int i = 0; i < 352; ++i) s = fmaf(flv[i], l1w[i * 128 + t], s);
        hmv[t] = s > 0.f ? s : 0.f;
    }
    __syncthreads();
    if (t < 64) {
        float v = fmaf(hmv[t], l2w[t], hmv[t + 64] * l2w[t + 64]);
#pragma unroll
        for (int o = 32; o > 0; o >>= 1) v += __shfl_down(v, o, 64);
        if (t == 0) out[g] = v + l2b[0];
    }
}

// ---------------- launch ----------------

extern "C" void kernel_launch(void* const* d_in, const int* in_sizes, int n_in,
                              void* d_out, int out_size, void* d_ws, size_t ws_size,
                              hipStream_t stream) {
    const int*   z   = (const int*)d_in[0];
    const int*   ei  = (const int*)d_in[1];
    const float* zt  = (const float*)d_in[3];
    const float* W0  = (const float*)d_in[4];
    const float* b0  = (const float*)d_in[5];
    const float* W1  = (const float*)d_in[6];
    const float* b1  = (const float*)d_in[7];
    const float* W2  = (const float*)d_in[8];
    const float* b2  = (const float*)d_in[9];
    const float* W3  = (const float*)d_in[10];
    const float* b3  = (const float*)d_in[11];
    const float* c1w = (const float*)d_in[12];
    const float* c1b = (const float*)d_in[13];
    const float* c2w = (const float*)d_in[14];
    const float* c2b = (const float*)d_in[15];
    const float* l1w = (const float*)d_in[16];
    const float* l1b = (const float*)d_in[17];
    const float* l2w = (const float*)d_in[18];
    const float* l2b = (const float*)d_in[19];
    float* out = (float*)d_out;

    const size_t ADJ_B = (size_t)NGRAPH * 4096 * 4;   // 16.78 MB
    if (ws_size < ADJ_B) {
        markWS_kernel<<<4, 256, 0, stream>>>(out);
        return;
    }

    unsigned* adjG = (unsigned*)d_ws;

    hipMemsetAsync(adjG, 0, ADJ_B, stream);
    adjscatter_kernel<<<(E_EDGES + 255) / 256, 256, 0, stream>>>(ei, adjG);

    gnn_kernel<<<NGRAPH, 512, 0, stream>>>(z, adjG, zt,
                                           W0, b0, W1, b1, W2, b2, W3, b3,
                                           c1w, c1b, c2w, c2b, l1w, l1b, l2w, l2b,
                                           out);
}